// Round 1
// baseline (9.410 us; speedup 1.0000x reference)
//
#include <hip/hip_runtime.h>

#define NF 64
#define RANK 16

__global__ __launch_bounds__(256) void MF_27436251087258_kernel(
    const int* __restrict__ users,
    const int* __restrict__ items,
    const float* __restrict__ user_emb,
    const float* __restrict__ item_emb,
    const float* __restrict__ user_bias,
    const float* __restrict__ item_bias,
    const float* __restrict__ A,
    const float* __restrict__ Bm,
    float* __restrict__ out,
    int batch)
{
    __shared__ float Bs[RANK * NF];   // 4 KB

    const int tid = threadIdx.x;

    // Stage B [16,64] into LDS: 1024 floats, 256 threads -> one float4 each.
    {
        const float4 v = ((const float4*)Bm)[tid];
        ((float4*)Bs)[tid] = v;
    }
    __syncthreads();

    const int group = tid >> 4;            // 16 groups of 16 lanes per block
    const int lane  = tid & 15;
    const int i = blockIdx.x * 16 + group; // output index
    if (i >= batch) return;                // grid is exact, but keep it safe

    const int u  = users[i];
    const int it = items[i];

    // Coalesced row gathers: 16 lanes x float4 = 64 floats per row.
    const float4 ue = *(const float4*)(user_emb + (size_t)u  * NF + lane * 4);
    const float4 ie = *(const float4*)(item_emb + (size_t)it * NF + lane * 4);
    const float  a  = A[(size_t)it * RANK + lane];   // 16 lanes x 1 float = A row

    // corr[f] = sum_r A[it,r] * B[r,f]  for this lane's 4 features.
    float c0 = 0.f, c1 = 0.f, c2 = 0.f, c3 = 0.f;
    #pragma unroll
    for (int r = 0; r < RANK; ++r) {
        const float ar = __shfl(a, r, 16);       // broadcast within 16-lane group
        const float4 br = ((const float4*)(Bs + r * NF))[lane];
        c0 = fmaf(ar, br.x, c0);
        c1 = fmaf(ar, br.y, c1);
        c2 = fmaf(ar, br.z, c2);
        c3 = fmaf(ar, br.w, c3);
    }

    // Partial dot: ue . (ie + corr)
    float p = ue.x * (ie.x + c0)
            + ue.y * (ie.y + c1)
            + ue.z * (ie.z + c2)
            + ue.w * (ie.w + c3);

    // Reduce across the 16-lane group.
    p += __shfl_xor(p, 8, 16);
    p += __shfl_xor(p, 4, 16);
    p += __shfl_xor(p, 2, 16);
    p += __shfl_xor(p, 1, 16);

    if (lane == 0) {
        out[i] = p + user_bias[u] + item_bias[it];
    }
}

extern "C" void kernel_launch(void* const* d_in, const int* in_sizes, int n_in,
                              void* d_out, int out_size, void* d_ws, size_t ws_size,
                              hipStream_t stream) {
    const int*   users     = (const int*)  d_in[0];
    const int*   items     = (const int*)  d_in[1];
    const float* user_emb  = (const float*)d_in[2];
    const float* item_emb  = (const float*)d_in[3];
    const float* user_bias = (const float*)d_in[4];
    const float* item_bias = (const float*)d_in[5];
    const float* A         = (const float*)d_in[6];
    const float* Bm        = (const float*)d_in[7];
    float* out = (float*)d_out;

    const int batch = in_sizes[0];             // 16384
    const int groups_per_block = 16;           // 256 threads / 16 lanes
    const int grid = (batch + groups_per_block - 1) / groups_per_block;

    MF_27436251087258_kernel<<<grid, 256, 0, stream>>>(
        users, items, user_emb, item_emb, user_bias, item_bias, A, Bm, out, batch);
}